// Round 6
// baseline (29.403 us; speedup 1.0000x reference)
//
#include <hip/hip_runtime.h>

// StructOnlyClassifier R6: single fused kernel, one wave per 4 graphs.
//  - lanes 0..4 run PARALLEL scalar windowed binary searches (quad int4
//    probes, +-8192 window around g*(n/B) with deterministic widen fallback)
//    -> ~12 dependent probes, ~13 cache lines per search (NOT R4's 64-line
//    wave-parallel thrash). 4096 waves = 16 waves/CU hide the probe latency
//    under other waves' streaming.
//  - wave then streams its 4 contiguous node_type segments (int4-coalesced),
//    counts types, and runs the 4->32->16->1 MLP (LDS weights, shfl h1).
// One launch, no workspace, no atomics.

constexpr int GPW = 4;   // graphs per wave

__global__ __launch_bounds__(256) void fused_kernel(
    const int* __restrict__ batch, const int* __restrict__ ntype,
    const float* __restrict__ W1, const float* __restrict__ b1,
    const float* __restrict__ W2, const float* __restrict__ b2,
    const float* __restrict__ W3, const float* __restrict__ b3,
    float* __restrict__ out, int n, int B)
{
    __shared__ float sW1[128], sW2[512], sb1[32], sb2[16], sW3[16], sb3v[1];
    const int tid = threadIdx.x;
    if (tid < 128) sW1[tid] = W1[tid];
    sW2[tid] = W2[tid];
    sW2[tid + 256] = W2[tid + 256];
    if      (tid < 32)  sb1[tid]      = b1[tid];
    else if (tid < 48)  sb2[tid - 32] = b2[tid - 32];
    else if (tid < 64)  sW3[tid - 48] = W3[tid - 48];
    else if (tid == 64) sb3v[0]       = b3[0];
    __syncthreads();

    const int wid  = (blockIdx.x * 256 + tid) >> 6;
    const int lane = tid & 63;
    const int g0   = wid * GPW;
    if (g0 >= B) return;

    // ---- parallel boundary searches on lanes 0..GPW ----
    int ans = 0;
    if (lane <= GPW) {
        const int g = min(g0 + lane, B);
        const long long c = (long long)g * (long long)(n / B); // predicted S[g]
        long long Wn = 8192;
        int lo, hi;
        for (;;) {                       // deterministic bracket (widen on miss)
            long long l = c - Wn; if (l < 0) l = 0;
            long long h = c + Wn + 3; if (h > n) h = n;
            lo = (int)l & ~3;
            hi = (int)h & ~3;            // n is a multiple of 4
            const bool okL = (lo == 0) || (batch[lo - 1] < g);
            const bool okR = (hi == n) || (batch[hi] >= g);
            if (okL && okR) break;
            Wn <<= 2;
        }
        // quad binary search; lo,hi stay multiples of 4, answer in [lo,hi]
        while (hi - lo > 4) {
            const int mid = ((lo + hi) >> 1) & ~3;   // in [lo+4, hi-4]
            const int4 q = *(const int4*)(batch + mid);
            if (q.w < g)       lo = mid + 4;
            else if (q.x >= g) hi = mid;
            else { lo = mid; hi = mid + 4; }         // straddles this quad
        }
        ans = lo;
        if (lo < hi) {                    // hi-lo == 4: count inside final quad
            const int4 q = *(const int4*)(batch + lo);
            ans = lo + (q.x < g) + (q.y < g) + (q.z < g) + (q.w < g);
        }
    }

    // ---- per-graph: coalesced segment count + MLP ----
    for (int i = 0; i < GPW; ++i) {
        const int g = g0 + i;
        if (g >= B) break;
        const int s   = __shfl(ans, i);
        const int e   = __shfl(ans, i + 1);
        const int len = e - s;

        int c0 = 0, c1 = 0;
        int sa = (s + 3) & ~3; if (sa > e) sa = e;
        int ea = e & ~3;       if (ea < sa) ea = sa;

        {   // head scalars [s, sa)
            const int idx = s + lane;
            if (idx < sa) { const int v = ntype[idx]; c0 += (v == 0); c1 += (v == 1); }
        }
        {   // main int4 quads [sa, ea), lane-contiguous
            const int4* nt4 = (const int4*)ntype;
            for (int q = (sa >> 2) + lane; q < (ea >> 2); q += 64) {
                const int4 v = nt4[q];
                c0 += (v.x == 0) + (v.y == 0) + (v.z == 0) + (v.w == 0);
                c1 += (v.x == 1) + (v.y == 1) + (v.z == 1) + (v.w == 1);
            }
        }
        {   // tail scalars [ea, e)
            const int idx = ea + lane;
            if (idx < e) { const int v = ntype[idx]; c0 += (v == 0); c1 += (v == 1); }
        }

        unsigned long long p = (unsigned)c0 | ((unsigned long long)(unsigned)c1 << 32);
        #pragma unroll
        for (int off = 32; off; off >>= 1) p += __shfl_xor(p, off);
        const int c0t = (int)(p & 0xFFFFFFFFull);
        const int c1t = (int)(p >> 32);

        const float f0 = (float)c0t - 54.5f;
        const float f1 = (float)c1t;
        const float f2 = (float)(len - c0t - c1t);
        const float f3 = (float)len - 56.5f;

        // layer 1: unit j on lane&31 (lanes 32-63 duplicate harmlessly)
        const int j = lane & 31;
        float h1 = sb1[j];
        h1 = fmaf(f0, sW1[      j], h1);
        h1 = fmaf(f1, sW1[ 32 + j], h1);
        h1 = fmaf(f2, sW1[ 64 + j], h1);
        h1 = fmaf(f3, sW1[ 96 + j], h1);
        h1 = fmaxf(0.0f, h1);

        // layer 2: unit m on lane&15, h1 broadcast via shfl, W2 from LDS
        const int m = lane & 15;
        float s2 = sb2[m];
        #pragma unroll
        for (int jj = 0; jj < 32; ++jj)
            s2 = fmaf(__shfl(h1, jj), sW2[jj * 16 + m], s2);
        const float h2 = fmaxf(0.0f, s2);

        // layer 3: reduce 16 units within the 16-lane group
        float p3 = h2 * sW3[m];
        p3 += __shfl_xor(p3, 8);
        p3 += __shfl_xor(p3, 4);
        p3 += __shfl_xor(p3, 2);
        p3 += __shfl_xor(p3, 1);

        if (lane == 0) out[g] = p3 + sb3v[0];
    }
}

extern "C" void kernel_launch(void* const* d_in, const int* in_sizes, int n_in,
                              void* d_out, int out_size, void* d_ws, size_t ws_size,
                              hipStream_t stream) {
    // inputs: 0:x(N) 1:batch(N) 2:node_type(N) 3:num_graphs 4:W1 5:b1 6:W2 7:b2 8:W3 9:b3
    const int*   batch = (const int*)d_in[1];
    const int*   ntype = (const int*)d_in[2];
    const float* W1    = (const float*)d_in[4];
    const float* b1    = (const float*)d_in[5];
    const float* W2    = (const float*)d_in[6];
    const float* b2    = (const float*)d_in[7];
    const float* W3    = (const float*)d_in[8];
    const float* b3    = (const float*)d_in[9];
    float*       out   = (float*)d_out;

    const int n = in_sizes[1];          // 16,777,216 nodes
    const int B = out_size;             // 16,384 graphs

    const int waves  = (B + GPW - 1) / GPW;          // 4096
    const int blocks = (waves * 64 + 255) / 256;     // 1024
    fused_kernel<<<blocks, 256, 0, stream>>>(
        batch, ntype, W1, b1, W2, b2, W3, b3, out, n, B);
}